// Round 3
// baseline (153.565 us; speedup 1.0000x reference)
//
#include <hip/hip_runtime.h>
#include <hip/hip_bf16.h>

// QueryAndGroupRRI: B=4, N=16384, M=2048, nsample=32, radius=0.1
// Inputs (float32): xyz (4,16384,3), new_xyz (4,2048,3)
// Output (float32): (4, 33, 2048, 32)  [dis_sort rows 0..31, grouped_r row 32]

#define BB 4
#define NN 16384
#define MM 2048
#define NS 32
#define R2 0.01f  // fp32-nearest of 0.1*0.1

__global__ __launch_bounds__(256) void qgr_kernel(
    const float* __restrict__ xyz,
    const float* __restrict__ nxyz,
    float* __restrict__ out) {

    // per-wave scratch: group coords + padded distance matrix (stride 33 -> no bank conflict)
    __shared__ float s_gx[4][NS], s_gy[4][NS], s_gz[4][NS];
    __shared__ float s_dis[4][NS][NS + 1];

    const int lane = threadIdx.x & 63;
    const int w = threadIdx.x >> 6;
    const int q = blockIdx.x * 4 + w;      // 0..8191
    const int b = q >> 11;                  // /2048
    const int m = q & (MM - 1);

    const float* xb = xyz + (size_t)b * NN * 3;
    const float* nq = nxyz + (size_t)q * 3;
    const float cx = nq[0], cy = nq[1], cz = nq[2];

    // ---- ball query: ordered append of first 32 in-ball points' coords ----
    int cnt = 0;
    for (int base = 0; base < NN; base += 64) {
        const float* p = xb + (size_t)(base + lane) * 3;
        float x = p[0], y = p[1], z = p[2];
        float dx = __fsub_rn(cx, x), dy = __fsub_rn(cy, y), dz = __fsub_rn(cz, z);
        float d2 = __fadd_rn(__fadd_rn(__fmul_rn(dx, dx), __fmul_rn(dy, dy)), __fmul_rn(dz, dz));
        bool in = d2 < R2;
        unsigned long long bal = __ballot(in);
        if (bal) {  // wave-uniform
            int rank = __popcll(bal & ((1ull << lane) - 1ull));
            int slot = cnt + rank;
            if (in && slot < NS) {
                s_gx[w][slot] = x; s_gy[w][slot] = y; s_gz[w][slot] = z;
            }
            cnt += __popcll(bal);
            if (cnt >= NS) break;  // wave-uniform
        }
    }
    __syncthreads();

    // ---- pad unfilled slots with slot-0 point (ref: idx==N -> first, then -> 0) ----
    int found = cnt < NS ? cnt : NS;
    float p0x, p0y, p0z;
    if (found == 0) { p0x = xb[0]; p0y = xb[1]; p0z = xb[2]; }
    else            { p0x = s_gx[w][0]; p0y = s_gy[w][0]; p0z = s_gz[w][0]; }
    if (lane < NS && lane >= found) {
        s_gx[w][lane] = p0x; s_gy[w][lane] = p0y; s_gz[w][lane] = p0z;
    }
    __syncthreads();

    // ---- pairwise distance matrix (exact np op order, no fma contraction) ----
    #pragma unroll
    for (int t = 0; t < 16; ++t) {
        int e = t * 64 + lane;
        int di = e >> 5, dj = e & 31;
        float dx = __fsub_rn(s_gx[w][di], s_gx[w][dj]);
        float dy = __fsub_rn(s_gy[w][di], s_gy[w][dj]);
        float dz = __fsub_rn(s_gz[w][di], s_gz[w][dj]);
        s_dis[w][di][dj] =
            sqrtf(__fadd_rn(__fadd_rn(__fmul_rn(dx, dx), __fmul_rn(dy, dy)), __fmul_rn(dz, dz)));
    }
    __syncthreads();

    // ---- row sums in numpy pairwise-8 order; argmax with first-occurrence tie-break ----
    {
        int i = lane & 31;  // lanes 32..63 duplicate rows 0..31 (harmless)
        float r[8];
        #pragma unroll
        for (int t = 0; t < 8; ++t) {
            r[t] = __fadd_rn(__fadd_rn(__fadd_rn(s_dis[w][i][t], s_dis[w][i][t + 8]),
                                        s_dis[w][i][t + 16]),
                             s_dis[w][i][t + 24]);
        }
        float mv = __fadd_rn(__fadd_rn(__fadd_rn(r[0], r[1]), __fadd_rn(r[2], r[3])),
                             __fadd_rn(__fadd_rn(r[4], r[5]), __fadd_rn(r[6], r[7])));
        int mi = i;
        #pragma unroll
        for (int off = 1; off < 64; off <<= 1) {
            float ov = __shfl_xor(mv, off);
            int oi = __shfl_xor(mi, off);
            if (ov > mv || (ov == mv && oi < mi)) { mv = ov; mi = oi; }
        }

        // tip point (broadcast LDS read)
        float tx = s_gx[w][mi], ty = s_gy[w][mi], tz = s_gz[w][mi];

        // tpv = normalize(cross(cross(c, tip), c))
        float ux = cy * tz - cz * ty, uy = cz * tx - cx * tz, uz = cx * ty - cy * tx;
        float vx = uy * cz - uz * cy, vy = uz * cx - ux * cz, vz = ux * cy - uy * cx;
        float vn = fmaxf(sqrtf(vx * vx + vy * vy + vz * vz), 1e-37f);
        float tnx = vx / vn, tny = vy / vn, tnz = vz / vn;

        // new_norm = c / (|c| + 1e-8)
        float nr = sqrtf(cx * cx + cy * cy + cz * cz);
        float dn = nr + 1e-8f;
        float nnx = cx / dn, nny = cy / dn, nnz = cz / dn;

        // ---- per-column j: sinv, grouped_r, sorted column ----
        int j = lane & 31;
        float gx = s_gx[w][j], gy = s_gy[w][j], gz = s_gz[w][j];

        // gpv = normalize(cross(cross(c, g), c))
        float ax = cy * gz - cz * gy, ay = cz * gx - cx * gz, az = cx * gy - cy * gx;
        float px = ay * cz - az * cy, py = az * cx - ax * cz, pz = ax * cy - ay * cx;
        float pn = fmaxf(sqrtf(px * px + py * py + pz * pz), 1e-37f);
        px /= pn; py /= pn; pz /= pn;

        // gcv = cross(gpv, tpv); sinv = dot(gcv, new_norm)
        float qx = py * tnz - pz * tny;
        float qy = pz * tnx - px * tnz;
        float qz = px * tny - py * tnx;
        float sinv = qx * nnx + qy * nny + qz * nnz;

        float gr = sqrtf(gx * gx + gy * gy + gz * gz);

        const size_t rowstride = (size_t)MM * NS;
        const size_t obase = (((size_t)b * 33) * MM + m) * NS + j;
        if (lane < NS) out[obase + 32 * rowstride] = gr;

        // load column j, bitonic sort ascending (fully unrolled, register-resident)
        float v[NS];
        #pragma unroll
        for (int ii = 0; ii < NS; ++ii) v[ii] = s_dis[w][ii][j];

        #pragma unroll
        for (int k = 2; k <= NS; k <<= 1) {
            #pragma unroll
            for (int jj = k >> 1; jj > 0; jj >>= 1) {
                #pragma unroll
                for (int ii = 0; ii < NS; ++ii) {
                    int ll = ii ^ jj;
                    if (ll > ii) {
                        bool up = ((ii & k) == 0);
                        float a = v[ii], c2 = v[ll];
                        bool sw = up ? (a > c2) : (a < c2);
                        if (sw) { v[ii] = c2; v[ll] = a; }
                    }
                }
            }
        }

        if (lane < NS) {
            #pragma unroll
            for (int ii = 0; ii < NS; ++ii)
                out[obase + (size_t)ii * rowstride] = v[ii] * sinv;
        }
    }
}

extern "C" void kernel_launch(void* const* d_in, const int* in_sizes, int n_in,
                              void* d_out, int out_size, void* d_ws, size_t ws_size,
                              hipStream_t stream) {
    (void)in_sizes; (void)n_in; (void)d_ws; (void)ws_size; (void)out_size;
    const float* xyz = (const float*)d_in[0];
    const float* nxyz = (const float*)d_in[1];
    float* out = (float*)d_out;
    // 8192 queries, 1 wave each, 4 waves/block
    qgr_kernel<<<(BB * MM) / 4, 256, 0, stream>>>(xyz, nxyz, out);
}

// Round 4
// 127.889 us; speedup vs baseline: 1.2008x; 1.2008x over previous
//
#include <hip/hip_runtime.h>
#include <hip/hip_bf16.h>

// QueryAndGroupRRI: B=4, N=16384, M=2048, nsample=32, radius=0.1
// Inputs (float32): xyz (4,16384,3), new_xyz (4,2048,3)
// Output (float32): (4, 33, 2048, 32)  [dis_sort rows 0..31, grouped_r row 32]

#define BB 4
#define NN 16384
#define MM 2048
#define NS 32
#define R2 0.01f   // fp32-nearest of 0.1*0.1
#define CHUNKS 4   // 4 x 64 = 256 points tested per scan iteration (ILP batching)

__global__ __launch_bounds__(256) void qgr_kernel(
    const float* __restrict__ xyz,
    const float* __restrict__ nxyz,
    float* __restrict__ out) {

    // per-wave scratch: group coords + padded distance matrix (stride 33 -> no bank conflict)
    __shared__ float s_gx[4][NS], s_gy[4][NS], s_gz[4][NS];
    __shared__ float s_dis[4][NS][NS + 1];

    const int lane = threadIdx.x & 63;
    const int w = threadIdx.x >> 6;
    const int q = blockIdx.x * 4 + w;      // 0..8191
    const int b = q >> 11;                  // /2048
    const int m = q & (MM - 1);

    const float* xb = xyz + (size_t)b * NN * 3;
    const float* nq = nxyz + (size_t)q * 3;
    const float cx = nq[0], cy = nq[1], cz = nq[2];

    const unsigned long long lmask = (1ull << lane) - 1ull;

    // ---- ball query: ordered append of first 32 in-ball points' coords ----
    // ILP: issue 3*CHUNKS loads up front per iteration, then process chunks in
    // index order. Early-exit granularity 256 points (overshoot writes guarded
    // by slot < NS, so ordering semantics are exact).
    int cnt = 0;
    for (int base = 0; base < NN; base += 64 * CHUNKS) {
        float X[CHUNKS], Y[CHUNKS], Z[CHUNKS];
        #pragma unroll
        for (int c = 0; c < CHUNKS; ++c) {
            const float* p = xb + (size_t)(base + c * 64 + lane) * 3;
            X[c] = p[0]; Y[c] = p[1]; Z[c] = p[2];
        }
        bool in[CHUNKS];
        #pragma unroll
        for (int c = 0; c < CHUNKS; ++c) {
            float dx = __fsub_rn(cx, X[c]);
            float dy = __fsub_rn(cy, Y[c]);
            float dz = __fsub_rn(cz, Z[c]);
            float d2 = __fadd_rn(__fadd_rn(__fmul_rn(dx, dx), __fmul_rn(dy, dy)),
                                 __fmul_rn(dz, dz));
            in[c] = d2 < R2;
        }
        #pragma unroll
        for (int c = 0; c < CHUNKS; ++c) {
            unsigned long long bal = __ballot(in[c]);
            if (bal) {  // wave-uniform
                int rank = __popcll(bal & lmask);
                int slot = cnt + rank;
                if (in[c] && slot < NS) {
                    s_gx[w][slot] = X[c]; s_gy[w][slot] = Y[c]; s_gz[w][slot] = Z[c];
                }
                cnt += __popcll(bal);
            }
        }
        if (cnt >= NS) break;  // wave-uniform
    }
    __syncthreads();

    // ---- pad unfilled slots with slot-0 point (ref: idx==N -> first, then -> 0) ----
    int found = cnt < NS ? cnt : NS;
    float p0x, p0y, p0z;
    if (found == 0) { p0x = xb[0]; p0y = xb[1]; p0z = xb[2]; }
    else            { p0x = s_gx[w][0]; p0y = s_gy[w][0]; p0z = s_gz[w][0]; }
    if (lane < NS && lane >= found) {
        s_gx[w][lane] = p0x; s_gy[w][lane] = p0y; s_gz[w][lane] = p0z;
    }
    __syncthreads();

    // ---- pairwise distance matrix (exact np op order, no fma contraction) ----
    #pragma unroll
    for (int t = 0; t < 16; ++t) {
        int e = t * 64 + lane;
        int di = e >> 5, dj = e & 31;
        float dx = __fsub_rn(s_gx[w][di], s_gx[w][dj]);
        float dy = __fsub_rn(s_gy[w][di], s_gy[w][dj]);
        float dz = __fsub_rn(s_gz[w][di], s_gz[w][dj]);
        s_dis[w][di][dj] =
            sqrtf(__fadd_rn(__fadd_rn(__fmul_rn(dx, dx), __fmul_rn(dy, dy)), __fmul_rn(dz, dz)));
    }
    __syncthreads();

    // ---- row sums in numpy pairwise-8 order; argmax with first-occurrence tie-break ----
    {
        int i = lane & 31;  // lanes 32..63 duplicate rows 0..31 (harmless)
        float r[8];
        #pragma unroll
        for (int t = 0; t < 8; ++t) {
            r[t] = __fadd_rn(__fadd_rn(__fadd_rn(s_dis[w][i][t], s_dis[w][i][t + 8]),
                                        s_dis[w][i][t + 16]),
                             s_dis[w][i][t + 24]);
        }
        float mv = __fadd_rn(__fadd_rn(__fadd_rn(r[0], r[1]), __fadd_rn(r[2], r[3])),
                             __fadd_rn(__fadd_rn(r[4], r[5]), __fadd_rn(r[6], r[7])));
        int mi = i;
        #pragma unroll
        for (int off = 1; off < 64; off <<= 1) {
            float ov = __shfl_xor(mv, off);
            int oi = __shfl_xor(mi, off);
            if (ov > mv || (ov == mv && oi < mi)) { mv = ov; mi = oi; }
        }

        // tip point (broadcast LDS read)
        float tx = s_gx[w][mi], ty = s_gy[w][mi], tz = s_gz[w][mi];

        // tpv = normalize(cross(cross(c, tip), c))
        float ux = cy * tz - cz * ty, uy = cz * tx - cx * tz, uz = cx * ty - cy * tx;
        float vx = uy * cz - uz * cy, vy = uz * cx - ux * cz, vz = ux * cy - uy * cx;
        float vn = fmaxf(sqrtf(vx * vx + vy * vy + vz * vz), 1e-37f);
        float tnx = vx / vn, tny = vy / vn, tnz = vz / vn;

        // new_norm = c / (|c| + 1e-8)
        float nr = sqrtf(cx * cx + cy * cy + cz * cz);
        float dn = nr + 1e-8f;
        float nnx = cx / dn, nny = cy / dn, nnz = cz / dn;

        // ---- per-column j: sinv, grouped_r, sorted column ----
        int j = lane & 31;
        float gx = s_gx[w][j], gy = s_gy[w][j], gz = s_gz[w][j];

        // gpv = normalize(cross(cross(c, g), c))
        float ax = cy * gz - cz * gy, ay = cz * gx - cx * gz, az = cx * gy - cy * gx;
        float px = ay * cz - az * cy, py = az * cx - ax * cz, pz = ax * cy - ay * cx;
        float pn = fmaxf(sqrtf(px * px + py * py + pz * pz), 1e-37f);
        px /= pn; py /= pn; pz /= pn;

        // gcv = cross(gpv, tpv); sinv = dot(gcv, new_norm)
        float qx = py * tnz - pz * tny;
        float qy = pz * tnx - px * tnz;
        float qz = px * tny - py * tnx;
        float sinv = qx * nnx + qy * nny + qz * nnz;

        float gr = sqrtf(gx * gx + gy * gy + gz * gz);

        const size_t rowstride = (size_t)MM * NS;
        const size_t obase = (((size_t)b * 33) * MM + m) * NS + j;
        if (lane < NS) out[obase + 32 * rowstride] = gr;

        // load column j, bitonic sort ascending (fully unrolled, register-resident)
        float v[NS];
        #pragma unroll
        for (int ii = 0; ii < NS; ++ii) v[ii] = s_dis[w][ii][j];

        #pragma unroll
        for (int k = 2; k <= NS; k <<= 1) {
            #pragma unroll
            for (int jj = k >> 1; jj > 0; jj >>= 1) {
                #pragma unroll
                for (int ii = 0; ii < NS; ++ii) {
                    int ll = ii ^ jj;
                    if (ll > ii) {
                        bool up = ((ii & k) == 0);
                        float a = v[ii], c2 = v[ll];
                        bool sw = up ? (a > c2) : (a < c2);
                        if (sw) { v[ii] = c2; v[ll] = a; }
                    }
                }
            }
        }

        if (lane < NS) {
            #pragma unroll
            for (int ii = 0; ii < NS; ++ii)
                out[obase + (size_t)ii * rowstride] = v[ii] * sinv;
        }
    }
}

extern "C" void kernel_launch(void* const* d_in, const int* in_sizes, int n_in,
                              void* d_out, int out_size, void* d_ws, size_t ws_size,
                              hipStream_t stream) {
    (void)in_sizes; (void)n_in; (void)d_ws; (void)ws_size; (void)out_size;
    const float* xyz = (const float*)d_in[0];
    const float* nxyz = (const float*)d_in[1];
    float* out = (float*)d_out;
    // 8192 queries, 1 wave each, 4 waves/block
    qgr_kernel<<<(BB * MM) / 4, 256, 0, stream>>>(xyz, nxyz, out);
}